// Round 25
// baseline (34.103 us; speedup 1.0000x reference)
//
#include <hip/hip_runtime.h>
#include <math.h>

// Problem constants (from reference):
constexpr int Bn = 1024;
constexpr int S  = 512;
constexpr int H  = 768;
constexpr int D1 = 128;
constexpr int HV = H / 4;     // 192 float4 per feature row
constexpr int K2 = 2 * H;     // 1536
constexpr int NK = K2 / 32;   // 48 K-tiles total
constexpr int NKH = 24;       // K-tiles per half
constexpr int NCAST = 8;      // W1 cast blocks (CRC half only)
constexpr int NCLS = 128;     // cls-head blocks (4 waves each = 512 tiles)

typedef _Float16 half8 __attribute__((ext_vector_type(8)));
typedef _Float16 half4v __attribute__((ext_vector_type(4)));
typedef float floatx4 __attribute__((ext_vector_type(4)));

// ws layout:
//   gcrc [1024][768] f16 — span means, LINEAR (1.5 MB)
//   w1s  [8][48][64][8] f16 — W1^T fragment order (only tiles 24..47 filled)
//   p0   [1024][128] f32 — CLS-half raw GEMM partials
//
// Fragment map: element (lane=lg*16+idx, e) of k-tile kk holds k = kk*32 +
// lg*8 + e. A and B use the SAME map, so any internal MFMA k-permutation
// cancels (validated R20-24, absmax 3.9e-3 = f16 rounding).

__device__ __forceinline__ size_t swz_off(int tile, int kk, int lg, int idx) {
  return ((((size_t)tile * NK + kk) * 64) + lg * 16 + idx) * 8;
}

// Launch 1 (R24-exact): [0,NCAST) cast W1 CRC half; [NCAST,+NCLS) cls-half
// MFMA head (self-cast from feat row 0 + W1); rest: pool -> gcrc.
__global__ __launch_bounds__(256) void launch1(
    const float* __restrict__ feat, const int* __restrict__ start,
    const int* __restrict__ endp, const float* __restrict__ W1,
    _Float16* __restrict__ gcrc, _Float16* __restrict__ w1s,
    float* __restrict__ p0) {
  __shared__ float4 pacc[4][3][64];   // 12 KB (pool path only)
  const int t = threadIdx.x;

  if (blockIdx.x < NCAST) {
    // ---- cast W1[768..1536)[128] -> w1s tiles 24..47 ----
    const int c  = blockIdx.x + 8;    // 96-row chunk index 8..15
    const int n  = t & 127;
    const int sb = t >> 7;            // 0/1
    const int nt = n >> 4, ni = n & 15;
    #pragma unroll
    for (int j = 0; j < 6; ++j) {
      const int k0 = c * 96 + sb * 48 + j * 8;   // 8-aligned, >= 768
      _Float16 h[8];
      #pragma unroll
      for (int i = 0; i < 8; ++i) {
        h[i] = (_Float16)W1[(size_t)(k0 + i) * D1 + n];  // coalesced per row
      }
      const int kk = k0 >> 5, lg = (k0 >> 3) & 3;
      *reinterpret_cast<half8*>(w1s + swz_off(nt, kk, lg, ni)) =
          *reinterpret_cast<half8*>(h);
    }
    return;
  }

  if (blockIdx.x < NCAST + NCLS) {
    // ---- CLS-half head (kh=0): wave = one 16x16 tile (eg, nt) ----
    const int w = t >> 6, l = t & 63;
    const int tid = (blockIdx.x - NCAST) * 4 + w;   // 0..511
    const int eg = tid & 63;
    const int nt = tid >> 6;
    const int lg = l >> 4, li = l & 15;
    const int e0 = eg * 16;
    const int n = nt * 16 + li;

    const float* arow = feat + (size_t)(e0 + li) * S * H;  // CLS row
    const float* wcol = W1 + n;

    floatx4 acc0 = {0.f, 0.f, 0.f, 0.f};
    floatx4 acc1 = {0.f, 0.f, 0.f, 0.f};
    #pragma unroll 2
    for (int kk = 0; kk < NKH; kk += 2) {
      #define MKFRAG(kkq, accq)                                            \
      {                                                                    \
        const int kb = (kkq) * 32 + lg * 8;                                \
        float4 fa = *reinterpret_cast<const float4*>(arow + kb);           \
        float4 fb = *reinterpret_cast<const float4*>(arow + kb + 4);       \
        const float* wb = wcol + (size_t)kb * D1;                          \
        float w0 = wb[0 * D1], w1v = wb[1 * D1], w2v = wb[2 * D1];         \
        float w3v = wb[3 * D1], w4v = wb[4 * D1], w5v = wb[5 * D1];        \
        float w6v = wb[6 * D1], w7v = wb[7 * D1];                          \
        half8 av, bv;                                                      \
        av[0] = (_Float16)fa.x; av[1] = (_Float16)fa.y;                    \
        av[2] = (_Float16)fa.z; av[3] = (_Float16)fa.w;                    \
        av[4] = (_Float16)fb.x; av[5] = (_Float16)fb.y;                    \
        av[6] = (_Float16)fb.z; av[7] = (_Float16)fb.w;                    \
        bv[0] = (_Float16)w0;  bv[1] = (_Float16)w1v;                      \
        bv[2] = (_Float16)w2v; bv[3] = (_Float16)w3v;                      \
        bv[4] = (_Float16)w4v; bv[5] = (_Float16)w5v;                      \
        bv[6] = (_Float16)w6v; bv[7] = (_Float16)w7v;                      \
        accq = __builtin_amdgcn_mfma_f32_16x16x32_f16(av, bv, accq, 0, 0, 0); \
      }
      MKFRAG(kk, acc0)
      MKFRAG(kk + 1, acc1)
      #undef MKFRAG
    }
    // C/D: col = li (n-local), row = lg*4 + r (example-local). [m89]
    #pragma unroll
    for (int r = 0; r < 4; ++r) {
      p0[(size_t)(e0 + lg * 4 + r) * D1 + n] = acc0[r] + acc1[r];
    }
    return;
  }

  // ---- pool (R23-exact body), writes CRC mean only -> gcrc linear ----
  const int b = blockIdx.x - (NCAST + NCLS);
  const int w = t >> 6;
  const int l = t & 63;
  const float4* base =
      reinterpret_cast<const float4*>(feat) + (size_t)b * (S * HV);

  const int s0 = start[b];
  const int s1 = endp[b];

  float4 c0{0,0,0,0}, c1{0,0,0,0}, c2{0,0,0,0};
  float4 d0{0,0,0,0}, d1{0,0,0,0}, d2{0,0,0,0};
  int s = s0 + w;
  for (; s + 4 < s1; s += 8) {
    const float4* r0 = base + (size_t)s * HV;
    const float4* r1 = base + (size_t)(s + 4) * HV;
    float4 u0 = r0[l], u1 = r0[l + 64], u2 = r0[l + 128];
    float4 v0 = r1[l], v1 = r1[l + 64], v2 = r1[l + 128];
    c0.x += u0.x; c0.y += u0.y; c0.z += u0.z; c0.w += u0.w;
    c1.x += u1.x; c1.y += u1.y; c1.z += u1.z; c1.w += u1.w;
    c2.x += u2.x; c2.y += u2.y; c2.z += u2.z; c2.w += u2.w;
    d0.x += v0.x; d0.y += v0.y; d0.z += v0.z; d0.w += v0.w;
    d1.x += v1.x; d1.y += v1.y; d1.z += v1.z; d1.w += v1.w;
    d2.x += v2.x; d2.y += v2.y; d2.z += v2.z; d2.w += v2.w;
  }
  for (; s < s1; s += 4) {
    const float4* r0 = base + (size_t)s * HV;
    float4 u0 = r0[l], u1 = r0[l + 64], u2 = r0[l + 128];
    c0.x += u0.x; c0.y += u0.y; c0.z += u0.z; c0.w += u0.w;
    c1.x += u1.x; c1.y += u1.y; c1.z += u1.z; c1.w += u1.w;
    c2.x += u2.x; c2.y += u2.y; c2.z += u2.z; c2.w += u2.w;
  }
  c0.x += d0.x; c0.y += d0.y; c0.z += d0.z; c0.w += d0.w;
  c1.x += d1.x; c1.y += d1.y; c1.z += d1.z; c1.w += d1.w;
  c2.x += d2.x; c2.y += d2.y; c2.z += d2.z; c2.w += d2.w;
  pacc[w][0][l] = c0;
  pacc[w][1][l] = c1;
  pacc[w][2][l] = c2;
  __syncthreads();

  if (t < 192) {
    const int seg = t >> 6, ln = t & 63;
    float4 a = pacc[0][seg][ln], bb = pacc[1][seg][ln];
    float4 cq = pacc[2][seg][ln], dq = pacc[3][seg][ln];
    const float inv = 1.0f / (float)(s1 - s0);
    half4v r;
    r.x = (_Float16)(((a.x + bb.x) + (cq.x + dq.x)) * inv);
    r.y = (_Float16)(((a.y + bb.y) + (cq.y + dq.y)) * inv);
    r.z = (_Float16)(((a.z + bb.z) + (cq.z + dq.z)) * inv);
    r.w = (_Float16)(((a.w + bb.w) + (cq.w + dq.w)) * inv);
    *reinterpret_cast<half4v*>(gcrc + (size_t)b * H + t * 4) = r;
  }
}

// Launch 2: CRC head + finalize fused. Block = one example-group (16 ex),
// 1024 thr = 16 waves; wave w = tile (nt = w>>1, kq = w&1), 12 k-tiles.
// Tiles -> LDS; barrier; wave w finalizes example w: h = b1 + p0(L2) +
// crc tiles; relu; *W2; butterfly; sigmoid -> out. No p1/p2, no 3rd launch.
__global__ __launch_bounds__(1024) void crc_fin(
    const _Float16* __restrict__ gcrc, const _Float16* __restrict__ w1s,
    const float* __restrict__ p0, const float* __restrict__ b1,
    const float* __restrict__ W2, const float* __restrict__ b2,
    float* __restrict__ out) {
  __shared__ float part[16][16][16];   // [tile=nt*2+kq][m][n_local], 16 KB

  const int t = threadIdx.x;
  const int w = t >> 6;               // wave 0..15
  const int l = t & 63;
  const int eg = blockIdx.x;
  const int e0 = eg * 16;
  const int nt = w >> 1;
  const int kq = w & 1;
  const int lg = l >> 4, li = l & 15;

  // A: gcrc[e0+li][(kq*12+kk)*32 + lg*8 + 0..7]
  const _Float16* Abase = gcrc + (size_t)(e0 + li) * H + kq * 384 + lg * 8;
  // B: fragment order, global k-tile = 24 + kq*12 + kk
  const half8* Bp = reinterpret_cast<const half8*>(w1s) +
                    ((size_t)nt * NK + NKH + kq * 12) * 64 + l;

  floatx4 acc0 = {0.f, 0.f, 0.f, 0.f};
  floatx4 acc1 = {0.f, 0.f, 0.f, 0.f};
  #pragma unroll 3
  for (int kk = 0; kk < 12; kk += 4) {  // 3 iters, 8 loads in flight
    half8 a0 = *reinterpret_cast<const half8*>(Abase + (kk + 0) * 32);
    half8 b0 = Bp[(size_t)(kk + 0) * 64];
    half8 a1 = *reinterpret_cast<const half8*>(Abase + (kk + 1) * 32);
    half8 b1v = Bp[(size_t)(kk + 1) * 64];
    half8 a2 = *reinterpret_cast<const half8*>(Abase + (kk + 2) * 32);
    half8 b2v = Bp[(size_t)(kk + 2) * 64];
    half8 a3 = *reinterpret_cast<const half8*>(Abase + (kk + 3) * 32);
    half8 b3v = Bp[(size_t)(kk + 3) * 64];
    acc0 = __builtin_amdgcn_mfma_f32_16x16x32_f16(a0, b0, acc0, 0, 0, 0);
    acc1 = __builtin_amdgcn_mfma_f32_16x16x32_f16(a1, b1v, acc1, 0, 0, 0);
    acc0 = __builtin_amdgcn_mfma_f32_16x16x32_f16(a2, b2v, acc0, 0, 0, 0);
    acc1 = __builtin_amdgcn_mfma_f32_16x16x32_f16(a3, b3v, acc1, 0, 0, 0);
  }

  // C/D: col = li (n-local), row = lg*4 + r (example-local). [m89]
  #pragma unroll
  for (int r = 0; r < 4; ++r) {
    part[w][lg * 4 + r][li] = acc0[r] + acc1[r];
  }
  __syncthreads();

  // Finalize: wave w = example e0+w; lane l owns n-pair (l, l+64).
  {
    const int e = e0 + w;
    const int n0 = l, n1 = l + 64;
    const int nl = l & 15;
    const int t0 = (l >> 4) * 2;          // tiles for n0: t0 (kq0), t0+1 (kq1)
    const int t1 = t0 + 8;                // tiles for n1
    const size_t pb = (size_t)e * D1;
    float h0 = b1[n0] + p0[pb + n0] + part[t0][w][nl] + part[t0 + 1][w][nl];
    float h1 = b1[n1] + p0[pb + n1] + part[t1][w][nl] + part[t1 + 1][w][nl];
    h0 = fmaxf(h0, 0.f); h1 = fmaxf(h1, 0.f);
    float v = h0 * W2[n0] + h1 * W2[n1];
    #pragma unroll
    for (int off = 32; off > 0; off >>= 1) v += __shfl_down(v, off);
    if (l == 0) out[e] = 1.0f / (1.0f + expf(-(v + b2[0])));
  }
}

extern "C" void kernel_launch(void* const* d_in, const int* in_sizes, int n_in,
                              void* d_out, int out_size, void* d_ws, size_t ws_size,
                              hipStream_t stream) {
  const float* feat = (const float*)d_in[0];   // [B,S,H] fp32
  const int* start  = (const int*)d_in[1];     // [B]
  const int* endp   = (const int*)d_in[2];     // [B]
  const float* W1   = (const float*)d_in[3];   // [2H,D1]
  const float* b1   = (const float*)d_in[4];   // [D1]
  const float* W2   = (const float*)d_in[5];   // [D1,1]
  const float* b2   = (const float*)d_in[6];   // [1]
  float* out = (float*)d_out;                  // [B]

  _Float16* gcrc = (_Float16*)d_ws;            // [1024][768]
  _Float16* w1s  = gcrc + (size_t)Bn * H;      // [8][48][64][8]
  float* p0 = (float*)(w1s + (size_t)D1 * K2); // [1024][128]

  hipLaunchKernelGGL(launch1, dim3(NCAST + NCLS + Bn), dim3(256), 0, stream,
                     feat, start, endp, W1, gcrc, w1s, p0);
  hipLaunchKernelGGL(crc_fin, dim3(64), dim3(1024), 0, stream,
                     gcrc, w1s, p0, b1, W2, b2, out);
}

// Round 26
// 30.561 us; speedup vs baseline: 1.1159x; 1.1159x over previous
//
#include <hip/hip_runtime.h>
#include <math.h>

// Problem constants (from reference):
constexpr int Bn = 1024;
constexpr int S  = 512;
constexpr int H  = 768;
constexpr int D1 = 128;
constexpr int HV = H / 4;     // 192 float4 per feature row
constexpr int K2 = 2 * H;     // 1536
constexpr int NK = K2 / 32;   // 48 K-tiles total
constexpr int NKH = 24;       // K-tiles per half
constexpr int NCAST = 8;      // W1 cast blocks (CRC half only)
constexpr int NCLS = 128;     // cls-head blocks (4 waves each = 512 tiles)

typedef _Float16 half8 __attribute__((ext_vector_type(8)));
typedef _Float16 half4v __attribute__((ext_vector_type(4)));
typedef float floatx4 __attribute__((ext_vector_type(4)));

// ws layout:
//   gcrc [1024][768] f16 — span means, LINEAR (1.5 MB)
//   w1s  [8][48][64][8] f16 — W1^T fragment order (only tiles 24..47 filled)
//   p0,p1,p2 [1024][128] f32 — raw GEMM partials (kh0, crc-q0, crc-q1)
//
// Fragment map: element (lane=lg*16+idx, e) of k-tile kk holds k = kk*32 +
// lg*8 + e. A and B use the SAME map, so any internal MFMA k-permutation
// cancels (validated R20-24, absmax 3.9e-3 = f16 rounding).

__device__ __forceinline__ size_t swz_off(int tile, int kk, int lg, int idx) {
  return ((((size_t)tile * NK + kk) * 64) + lg * 16 + idx) * 8;
}

// Launch 1: [0,NCAST) cast W1 CRC half; [NCAST,+NCLS) cls-half head
// (self-cast from feat row 0 + W1 — no staging dependency); rest: pool.
__global__ __launch_bounds__(256) void launch1(
    const float* __restrict__ feat, const int* __restrict__ start,
    const int* __restrict__ endp, const float* __restrict__ W1,
    _Float16* __restrict__ gcrc, _Float16* __restrict__ w1s,
    float* __restrict__ p0) {
  __shared__ float4 pacc[4][3][64];   // 12 KB (pool path only)
  const int t = threadIdx.x;

  if (blockIdx.x < NCAST) {
    // ---- cast W1[768..1536)[128] -> w1s tiles 24..47 ----
    const int c  = blockIdx.x + 8;    // 96-row chunk index 8..15
    const int n  = t & 127;
    const int sb = t >> 7;            // 0/1
    const int nt = n >> 4, ni = n & 15;
    #pragma unroll
    for (int j = 0; j < 6; ++j) {
      const int k0 = c * 96 + sb * 48 + j * 8;   // 8-aligned, >= 768
      _Float16 h[8];
      #pragma unroll
      for (int i = 0; i < 8; ++i) {
        h[i] = (_Float16)W1[(size_t)(k0 + i) * D1 + n];  // coalesced per row
      }
      const int kk = k0 >> 5, lg = (k0 >> 3) & 3;
      *reinterpret_cast<half8*>(w1s + swz_off(nt, kk, lg, ni)) =
          *reinterpret_cast<half8*>(h);
    }
    return;
  }

  if (blockIdx.x < NCAST + NCLS) {
    // ---- CLS-half head (kh=0): wave = one 16x16 tile (eg, nt) ----
    const int w = t >> 6, l = t & 63;
    const int tid = (blockIdx.x - NCAST) * 4 + w;   // 0..511
    const int eg = tid & 63;
    const int nt = tid >> 6;
    const int lg = l >> 4, li = l & 15;
    const int e0 = eg * 16;
    const int n = nt * 16 + li;

    const float* arow = feat + (size_t)(e0 + li) * S * H;  // CLS row
    const float* wcol = W1 + n;

    floatx4 acc0 = {0.f, 0.f, 0.f, 0.f};
    floatx4 acc1 = {0.f, 0.f, 0.f, 0.f};
    #pragma unroll 2
    for (int kk = 0; kk < NKH; kk += 2) {
      #define MKFRAG(kkq, accq)                                            \
      {                                                                    \
        const int kb = (kkq) * 32 + lg * 8;                                \
        float4 fa = *reinterpret_cast<const float4*>(arow + kb);           \
        float4 fb = *reinterpret_cast<const float4*>(arow + kb + 4);       \
        const float* wb = wcol + (size_t)kb * D1;                          \
        float w0 = wb[0 * D1], w1v = wb[1 * D1], w2v = wb[2 * D1];         \
        float w3v = wb[3 * D1], w4v = wb[4 * D1], w5v = wb[5 * D1];        \
        float w6v = wb[6 * D1], w7v = wb[7 * D1];                          \
        half8 av, bv;                                                      \
        av[0] = (_Float16)fa.x; av[1] = (_Float16)fa.y;                    \
        av[2] = (_Float16)fa.z; av[3] = (_Float16)fa.w;                    \
        av[4] = (_Float16)fb.x; av[5] = (_Float16)fb.y;                    \
        av[6] = (_Float16)fb.z; av[7] = (_Float16)fb.w;                    \
        bv[0] = (_Float16)w0;  bv[1] = (_Float16)w1v;                      \
        bv[2] = (_Float16)w2v; bv[3] = (_Float16)w3v;                      \
        bv[4] = (_Float16)w4v; bv[5] = (_Float16)w5v;                      \
        bv[6] = (_Float16)w6v; bv[7] = (_Float16)w7v;                      \
        accq = __builtin_amdgcn_mfma_f32_16x16x32_f16(av, bv, accq, 0, 0, 0); \
      }
      MKFRAG(kk, acc0)
      MKFRAG(kk + 1, acc1)
      #undef MKFRAG
    }
    // C/D: col = li (n-local), row = lg*4 + r (example-local). [m89]
    #pragma unroll
    for (int r = 0; r < 4; ++r) {
      p0[(size_t)(e0 + lg * 4 + r) * D1 + n] = acc0[r] + acc1[r];
    }
    return;
  }

  // ---- pool (R23-exact body), writes CRC mean only -> gcrc linear ----
  const int b = blockIdx.x - (NCAST + NCLS);
  const int w = t >> 6;
  const int l = t & 63;
  const float4* base =
      reinterpret_cast<const float4*>(feat) + (size_t)b * (S * HV);

  const int s0 = start[b];
  const int s1 = endp[b];

  float4 c0{0,0,0,0}, c1{0,0,0,0}, c2{0,0,0,0};
  float4 d0{0,0,0,0}, d1{0,0,0,0}, d2{0,0,0,0};
  int s = s0 + w;
  for (; s + 4 < s1; s += 8) {
    const float4* r0 = base + (size_t)s * HV;
    const float4* r1 = base + (size_t)(s + 4) * HV;
    float4 u0 = r0[l], u1 = r0[l + 64], u2 = r0[l + 128];
    float4 v0 = r1[l], v1 = r1[l + 64], v2 = r1[l + 128];
    c0.x += u0.x; c0.y += u0.y; c0.z += u0.z; c0.w += u0.w;
    c1.x += u1.x; c1.y += u1.y; c1.z += u1.z; c1.w += u1.w;
    c2.x += u2.x; c2.y += u2.y; c2.z += u2.z; c2.w += u2.w;
    d0.x += v0.x; d0.y += v0.y; d0.z += v0.z; d0.w += v0.w;
    d1.x += v1.x; d1.y += v1.y; d1.z += v1.z; d1.w += v1.w;
    d2.x += v2.x; d2.y += v2.y; d2.z += v2.z; d2.w += v2.w;
  }
  for (; s < s1; s += 4) {
    const float4* r0 = base + (size_t)s * HV;
    float4 u0 = r0[l], u1 = r0[l + 64], u2 = r0[l + 128];
    c0.x += u0.x; c0.y += u0.y; c0.z += u0.z; c0.w += u0.w;
    c1.x += u1.x; c1.y += u1.y; c1.z += u1.z; c1.w += u1.w;
    c2.x += u2.x; c2.y += u2.y; c2.z += u2.z; c2.w += u2.w;
  }
  c0.x += d0.x; c0.y += d0.y; c0.z += d0.z; c0.w += d0.w;
  c1.x += d1.x; c1.y += d1.y; c1.z += d1.z; c1.w += d1.w;
  c2.x += d2.x; c2.y += d2.y; c2.z += d2.z; c2.w += d2.w;
  pacc[w][0][l] = c0;
  pacc[w][1][l] = c1;
  pacc[w][2][l] = c2;
  __syncthreads();

  if (t < 192) {
    const int seg = t >> 6, ln = t & 63;
    float4 a = pacc[0][seg][ln], bb = pacc[1][seg][ln];
    float4 cq = pacc[2][seg][ln], dq = pacc[3][seg][ln];
    const float inv = 1.0f / (float)(s1 - s0);
    half4v r;
    r.x = (_Float16)(((a.x + bb.x) + (cq.x + dq.x)) * inv);
    r.y = (_Float16)(((a.y + bb.y) + (cq.y + dq.y)) * inv);
    r.z = (_Float16)(((a.z + bb.z) + (cq.z + dq.z)) * inv);
    r.w = (_Float16)(((a.w + bb.w) + (cq.w + dq.w)) * inv);
    *reinterpret_cast<half4v*>(gcrc + (size_t)b * H + t * 4) = r;
  }
}

// Launch 2: CRC head, k-quarter split. Grid 1024 x 64; wave = (eg, nt, kq).
// bid = ((nt*2+kq)*64 + eg) => bid%8 == eg%8 (XCD locality on gcrc panel).
__global__ __launch_bounds__(64) void crc_mfma(
    const _Float16* __restrict__ gcrc, const _Float16* __restrict__ w1s,
    float* __restrict__ p1, float* __restrict__ p2) {
  const int l  = threadIdx.x;
  const int eg = blockIdx.x & 63;
  const int rest = blockIdx.x >> 6;   // 0..15
  const int nt = rest >> 1;
  const int kq = rest & 1;

  const int lg = l >> 4, li = l & 15;
  const int e0 = eg * 16;

  // A: gcrc[e0+li][(kq*12+kk)*32 + lg*8 + 0..7]
  const _Float16* Abase = gcrc + (size_t)(e0 + li) * H + kq * 384 + lg * 8;
  // B: fragment order, global k-tile = 24 + kq*12 + kk
  const half8* Bp = reinterpret_cast<const half8*>(w1s) +
                    ((size_t)nt * NK + NKH + kq * 12) * 64 + l;

  floatx4 acc0 = {0.f, 0.f, 0.f, 0.f};
  floatx4 acc1 = {0.f, 0.f, 0.f, 0.f};
  #pragma unroll 3
  for (int kk = 0; kk < 12; kk += 4) {  // 3 iters, 8 loads in flight
    half8 a0 = *reinterpret_cast<const half8*>(Abase + (kk + 0) * 32);
    half8 b0 = Bp[(size_t)(kk + 0) * 64];
    half8 a1 = *reinterpret_cast<const half8*>(Abase + (kk + 1) * 32);
    half8 b1v = Bp[(size_t)(kk + 1) * 64];
    half8 a2 = *reinterpret_cast<const half8*>(Abase + (kk + 2) * 32);
    half8 b2v = Bp[(size_t)(kk + 2) * 64];
    half8 a3 = *reinterpret_cast<const half8*>(Abase + (kk + 3) * 32);
    half8 b3v = Bp[(size_t)(kk + 3) * 64];
    acc0 = __builtin_amdgcn_mfma_f32_16x16x32_f16(a0, b0, acc0, 0, 0, 0);
    acc1 = __builtin_amdgcn_mfma_f32_16x16x32_f16(a1, b1v, acc1, 0, 0, 0);
    acc0 = __builtin_amdgcn_mfma_f32_16x16x32_f16(a2, b2v, acc0, 0, 0, 0);
    acc1 = __builtin_amdgcn_mfma_f32_16x16x32_f16(a3, b3v, acc1, 0, 0, 0);
  }

  float* plane = kq ? p2 : p1;
  const int n = nt * 16 + li;
  #pragma unroll
  for (int r = 0; r < 4; ++r) {
    plane[(size_t)(e0 + lg * 4 + r) * D1 + n] = acc0[r] + acc1[r];
  }
}

// Launch 3: fin — wave per example; lane owns k-pair; 3 partial planes.
__global__ __launch_bounds__(256) void fin(
    const float* __restrict__ p0, const float* __restrict__ p1,
    const float* __restrict__ p2, const float* __restrict__ b1,
    const float* __restrict__ W2, const float* __restrict__ b2,
    float* __restrict__ out) {
  const int t = threadIdx.x;
  const int w = t >> 6, l = t & 63;
  const int e = blockIdx.x * 4 + w;
  const int k0 = l, k1 = l + 64;
  const size_t base = (size_t)e * D1;
  float h0 = b1[k0] + p0[base + k0] + p1[base + k0] + p2[base + k0];
  float h1 = b1[k1] + p0[base + k1] + p1[base + k1] + p2[base + k1];
  h0 = fmaxf(h0, 0.f); h1 = fmaxf(h1, 0.f);
  float v = h0 * W2[k0] + h1 * W2[k1];
  #pragma unroll
  for (int off = 32; off > 0; off >>= 1) v += __shfl_down(v, off);
  if (l == 0) out[e] = 1.0f / (1.0f + expf(-(v + b2[0])));
}

extern "C" void kernel_launch(void* const* d_in, const int* in_sizes, int n_in,
                              void* d_out, int out_size, void* d_ws, size_t ws_size,
                              hipStream_t stream) {
  const float* feat = (const float*)d_in[0];   // [B,S,H] fp32
  const int* start  = (const int*)d_in[1];     // [B]
  const int* endp   = (const int*)d_in[2];     // [B]
  const float* W1   = (const float*)d_in[3];   // [2H,D1]
  const float* b1   = (const float*)d_in[4];   // [D1]
  const float* W2   = (const float*)d_in[5];   // [D1,1]
  const float* b2   = (const float*)d_in[6];   // [1]
  float* out = (float*)d_out;                  // [B]

  _Float16* gcrc = (_Float16*)d_ws;            // [1024][768]
  _Float16* w1s  = gcrc + (size_t)Bn * H;      // [8][48][64][8]
  float* p0 = (float*)(w1s + (size_t)D1 * K2); // [1024][128]
  float* p1 = p0 + (size_t)Bn * D1;
  float* p2 = p1 + (size_t)Bn * D1;

  hipLaunchKernelGGL(launch1, dim3(NCAST + NCLS + Bn), dim3(256), 0, stream,
                     feat, start, endp, W1, gcrc, w1s, p0);
  hipLaunchKernelGGL(crc_mfma, dim3(1024), dim3(64), 0, stream,
                     gcrc, w1s, p1, p2);
  hipLaunchKernelGGL(fin, dim3(Bn / 4), dim3(256), 0, stream,
                     p0, p1, p2, b1, W2, b2, out);
}